// Round 2
// baseline (268.082 us; speedup 1.0000x reference)
//
#include <hip/hip_runtime.h>
#include <float.h>
#include <stdint.h>

// WindowRouting: out[b][q][0..3] = indices of top-4 of (Q[b,q,:] . I[b,m,:]) over m.
// Scale dropped (order-preserving).
//
// K0 (wr_cvt): fp32 -> bf16, DIRECT (no LDS/sync). One thread = one int4 of the
//   fragment-linear ib layout (gathers 32B of an image row; wave-coalesced into
//   16 full 128B lines), or 8 query elements.
// K1 (wr_mfma): 256 blocks x 512 thr. Block = 64 q x all 8192 m; wave = m-eighth.
//   R10: R8's proven register-resident step structure (local f32x4 a[4] inside
//   the step lambda, selection inline after MFMA+refill -- R9's pointer-passed
//   ping-pong score arrays defeated SROA and spilled to scratch: 175MB
//   WRITE_SIZE, 3x regression). Kept from R9 (both validated by harness):
//   (a) group-max screen: per strip per step, insert only max of the lane's 4
//       consecutive m (one group) into the top-4 chain; low 11 bits = group key
//       2047 - (4h+quad). Refine expands top-8 GROUPS x 4 m = 32 fp64 cands/row.
//   (b) hoisted zero C-operand for the first ks (no accvgpr zero-init per step).
//   3-deep rotating image ring unchanged (consume R before refill).
// Fallback: fp32 LDS-tiled kernel if ws too small (unchanged).

#define NBATCH 4
#define NQ 4096
#define NM 8192
#define KD 128

typedef unsigned short ushort_t;
typedef __attribute__((ext_vector_type(8))) short bf16x8;
typedef __attribute__((ext_vector_type(4))) float f32x4;

#define BETTER64(v, i, w, j) (((v) > (w)) || ((v) == (w) && (i) < (j)))

__device__ inline float fmed3(float a, float b, float c) {
#if __has_builtin(__builtin_amdgcn_fmed3f)
  return __builtin_amdgcn_fmed3f(a, b, c);
#else
  return fmaxf(fminf(a, b), fminf(fmaxf(a, b), c));
#endif
}

__device__ inline ushort_t f2bf(float f) {
  unsigned u = __float_as_uint(f);
  u += 0x7fffu + ((u >> 16) & 1u);  // RNE
  return (ushort_t)(u >> 16);
}

__device__ inline unsigned pk2(float a, float b) {
  return (unsigned)f2bf(a) | ((unsigned)f2bf(b) << 16);
}

// ---------------- K0: direct convert + swizzle (no LDS) ----------------
// ib flat int4 index t (within batch): tt = tile*512 + htl*256 + ks*64 + l
//   -> row m = tile*32 + htl*16 + (l&15), k0 = ks*32 + (l>>4)*8, 8 bf16 elems.
__global__ __launch_bounds__(256) void wr_cvt(const float* __restrict__ qry,
                                              const float* __restrict__ img,
                                              ushort_t* __restrict__ qb,
                                              int4* __restrict__ ib) {
  const int t = (int)blockIdx.x * 256 + (int)threadIdx.x;  // 0..786431
  if (t < 524288) {
    // image: one ib int4 per thread
    const int b = t >> 17;
    const int tt = t & 131071;
    const int tile = tt >> 9;
    const int n = tt & 511;
    const int l = n & 63;
    const int m = tile * 32 + (n >> 8) * 16 + (l & 15);
    const int k0 = ((n >> 6) & 3) * 32 + ((l >> 4) & 3) * 8;
    const float* src = img + ((size_t)(b * NM + m)) * KD + k0;
    const float4 v0 = *(const float4*)(src);
    const float4 v1 = *(const float4*)(src + 4);
    int4 o;
    o.x = (int)pk2(v0.x, v0.y);
    o.y = (int)pk2(v0.z, v0.w);
    o.z = (int)pk2(v1.x, v1.y);
    o.w = (int)pk2(v1.z, v1.w);
    ib[t] = o;
  } else {
    // query: 8 elements per thread, linear
    const int u = t - 524288;  // 0..262143
    const float4 v0 = ((const float4*)qry)[2 * u];
    const float4 v1 = ((const float4*)qry)[2 * u + 1];
    int4 o;
    o.x = (int)pk2(v0.x, v0.y);
    o.y = (int)pk2(v0.z, v0.w);
    o.z = (int)pk2(v1.x, v1.y);
    o.w = (int)pk2(v1.z, v1.w);
    ((int4*)qb)[u] = o;
  }
}

// ---------------- K1: MFMA screen (group-max) + fp64 refine ----------------
__global__ __launch_bounds__(512, 1) void wr_mfma(const float* __restrict__ qry,
                                                  const float* __restrict__ img,
                                                  const ushort_t* __restrict__ qb,
                                                  const int4* __restrict__ ib,
                                                  int* __restrict__ out) {
  const int bid = (int)blockIdx.x;               // 0..255
  const int b = (bid & 7) >> 1;                  // batch pinned to XCD pair
  const int qt = ((bid >> 3) << 1) | (bid & 1);  // 0..63
  const int qbase = qt * 64;

  const int tid = (int)threadIdx.x;
  const int lane = tid & 63;
  const int w = tid >> 6;        // 0..7 -> m-eighth (64 half-tiles of 16 m)
  const int q15 = lane & 15;
  const int quad = lane >> 4;    // 0..3

  const ushort_t* Qb = qb + ((size_t)b * NQ + qbase) * KD;
  const int4* ibc = ib + (size_t)b * 131072;

  // query fragments pinned: 4 strips of 16 q. B[n=q15][k = ks*32 + quad*8 + j]
  bf16x8 bfrag[4][4];  // [strip][ks] -> 64 VGPRs
#pragma unroll
  for (int s = 0; s < 4; ++s)
#pragma unroll
    for (int ks = 0; ks < 4; ++ks)
      bfrag[s][ks] =
          *(const bf16x8*)(Qb + (size_t)(s * 16 + q15) * KD + ks * 32 + quad * 8);

  float tch[4][4];  // one packed GROUP-key top-4 chain per strip
#pragma unroll
  for (int s = 0; s < 4; ++s)
#pragma unroll
    for (int e = 0; e < 4; ++e) tch[s][e] = -FLT_MAX;

  bf16x8 B0[4], B1[4], B2[4];  // 3-deep ring, 16 regs each

  auto loadH = [&](bf16x8* R, int h) {
    const int4* p = ibc + (((w * 64 + h) << 8) + lane);
#pragma unroll
    for (int ks = 0; ks < 4; ++ks) R[ks] = *(const bf16x8*)(p + ks * 64);
  };

  const f32x4 z4 = {0.f, 0.f, 0.f, 0.f};  // hoisted zero acc

  int hl = 3;
  int gb = 2047 - quad;  // group key base; group id = 4h + quad (< 256)

  auto step = [&](bf16x8* R) {
    f32x4 a[4];
    // all 16 MFMAs consume R before the refill below (ring-reuse hazard)
#pragma unroll
    for (int s = 0; s < 4; ++s)
      a[s] = __builtin_amdgcn_mfma_f32_16x16x32_bf16(R[0], bfrag[s][0], z4,
                                                     0, 0, 0);
#pragma unroll
    for (int ks = 1; ks < 4; ++ks)
#pragma unroll
      for (int s = 0; s < 4; ++s)
        a[s] = __builtin_amdgcn_mfma_f32_16x16x32_bf16(R[ks], bfrag[s][ks],
                                                       a[s], 0, 0, 0);
    if (hl < 64) loadH(R, hl);  // refill for use 3 steps later
    ++hl;
#pragma unroll
    for (int s = 0; s < 4; ++s) {
      const float gm =
          fmaxf(fmaxf(a[s][0], a[s][1]), fmaxf(a[s][2], a[s][3]));
      const float k =
          __uint_as_float((__float_as_uint(gm) & 0xFFFFF800u) | (unsigned)gb);
      tch[s][3] = fmed3(k, tch[s][2], tch[s][3]);
      tch[s][2] = fmed3(k, tch[s][1], tch[s][2]);
      tch[s][1] = fmed3(k, tch[s][0], tch[s][1]);
      tch[s][0] = fmaxf(tch[s][0], k);
    }
    gb -= 4;
  };

  loadH(B0, 0);
  loadH(B1, 1);
  loadH(B2, 2);
  for (int g = 0; g < 21; ++g) { step(B0); step(B1); step(B2); }
  step(B0);  // half-tile 63

  // ---- quad-tree merge per strip (snapshot donor regs BEFORE mutating) ----
#pragma unroll
  for (int s = 0; s < 4; ++s) {
    float k4[4];
#pragma unroll
    for (int e = 0; e < 4; ++e) k4[e] = __shfl_down(tch[s][e], 32, 64);
#pragma unroll
    for (int e = 0; e < 4; ++e) {
      const float k = k4[e];
      tch[s][3] = fmed3(k, tch[s][2], tch[s][3]);
      tch[s][2] = fmed3(k, tch[s][1], tch[s][2]);
      tch[s][1] = fmed3(k, tch[s][0], tch[s][1]);
      tch[s][0] = fmaxf(tch[s][0], k);
    }
#pragma unroll
    for (int e = 0; e < 4; ++e) k4[e] = __shfl_down(tch[s][e], 16, 64);
#pragma unroll
    for (int e = 0; e < 4; ++e) {
      const float k = k4[e];
      tch[s][3] = fmed3(k, tch[s][2], tch[s][3]);
      tch[s][2] = fmed3(k, tch[s][1], tch[s][2]);
      tch[s][1] = fmed3(k, tch[s][0], tch[s][1]);
      tch[s][0] = fmaxf(tch[s][0], k);
    }
  }

  // ---- 32 candidate GROUPS per q-row (8 eighths x 4), 64 rows ----
  __shared__ float ck[64][33];
  __shared__ int top8[64][8];     // group base m (batch-local)
  __shared__ double pd[64][33];   // 32 refined values (+pad)
  __shared__ int pi[64][33];

  if (lane < 16) {
#pragma unroll
    for (int s = 0; s < 4; ++s)
#pragma unroll
      for (int e = 0; e < 4; ++e) ck[s * 16 + q15][w * 4 + e] = tch[s][e];
  }
  __syncthreads();

  // ---- rank-select top-8 of 32 packed group keys per row (ranks unique) ----
  for (int p = tid; p < 2048; p += 512) {
    const int q = p >> 5;
    const int j = p & 31;
    const float k = ck[q][j];
    int rank = 0;
#pragma unroll 8
    for (int i = 0; i < 32; ++i) {
      const float o = ck[q][i];
      rank += (o > k) || (o == k && i < j);
    }
    if (rank < 8) {
      const unsigned bits = __float_as_uint(k);
      // glocal = 2047 - low11; m_base = eighth*1024 + glocal*4
      top8[q][rank] = (j >> 2) * 1024 + (2047 - (int)(bits & 0x7FFu)) * 4;
    }
  }
  __syncthreads();

  // ---- fp64 refine: one GROUP (4 m) per thread (64 rows x 8 groups) ----
  {
    const int q = tid >> 3;
    const int slot = tid & 7;
    const int mb = top8[q][slot];
    const float* qrow = qry + ((size_t)b * NQ + qbase + q) * KD;
#pragma unroll
    for (int jj = 0; jj < 4; ++jj) {
      const int m = mb + jj;
      const float* irow = img + ((size_t)b * NM + m) * KD;
      double s0 = 0.0, s1 = 0.0, s2 = 0.0, s3 = 0.0;
#pragma unroll
      for (int k = 0; k < KD; k += 4) {
        const float4 xv = *(const float4*)(qrow + k);
        const float4 yv = *(const float4*)(irow + k);
        s0 = fma((double)xv.x, (double)yv.x, s0);
        s1 = fma((double)xv.y, (double)yv.y, s1);
        s2 = fma((double)xv.z, (double)yv.z, s2);
        s3 = fma((double)xv.w, (double)yv.w, s3);
      }
      pd[q][slot * 4 + jj] = (s0 + s1) + (s2 + s3);
      pi[q][slot * 4 + jj] = m;
    }
  }
  __syncthreads();

  // ---- exact top-4 of 32 refined, (value desc, index asc) ----
  if (tid < 64) {
    const int q = tid;
    double fv[4];
    int fi[4];
#pragma unroll
    for (int e = 0; e < 4; ++e) { fv[e] = -DBL_MAX; fi[e] = 0x7fffffff; }
    for (int sl = 0; sl < 32; ++sl) {
      const double v = pd[q][sl];
      const int m = pi[q][sl];
      const bool b0 = BETTER64(v, m, fv[0], fi[0]);
      const bool b1 = BETTER64(v, m, fv[1], fi[1]);
      const bool b2 = BETTER64(v, m, fv[2], fi[2]);
      const bool b3 = BETTER64(v, m, fv[3], fi[3]);
      fv[3] = b2 ? fv[2] : (b3 ? v : fv[3]);
      fi[3] = b2 ? fi[2] : (b3 ? m : fi[3]);
      fv[2] = b1 ? fv[1] : (b2 ? v : fv[2]);
      fi[2] = b1 ? fi[1] : (b2 ? m : fi[2]);
      fv[1] = b0 ? fv[0] : (b1 ? v : fv[1]);
      fi[1] = b0 ? fi[0] : (b1 ? m : fi[1]);
      fv[0] = b0 ? v : fv[0];
      fi[0] = b0 ? m : fi[0];
    }
    int4 o;
    o.x = fi[0]; o.y = fi[1]; o.z = fi[2]; o.w = fi[3];
    *(int4*)(out + ((size_t)b * NQ + qbase + q) * 4) = o;
  }
}

// ---------------- Fallback: fp32 LDS-tiled kernel (ws too small) ----------------
#define QT 64
#define MT 128
#define KC 64
#define NTHREADS 512

__global__ __launch_bounds__(NTHREADS) void wr_main(const float* __restrict__ qry,
                                                    const float* __restrict__ img,
                                                    int* __restrict__ out) {
  __shared__ __align__(16) float A_lds[KD * QT];
  __shared__ __align__(16) float B_lds[KC * MT];

  const int t = (int)threadIdx.x;
  const int b = (int)blockIdx.x >> 6;
  const int qbase = ((int)blockIdx.x & 63) * QT;

  const float* qp = qry + ((size_t)b * NQ + qbase) * KD;
  const float* ip = img + (size_t)b * NM * KD;

  {
    const int r = t >> 3;
    const int kc = t & 7;
    const float* src = qp + (size_t)r * KD;
#pragma unroll
    for (int i = 0; i < 4; ++i) {
      const int k0 = kc * 4 + i * 32;
      const float4 v = *(const float4*)(src + k0);
      A_lds[(k0 + 0) * QT + r] = v.x;
      A_lds[(k0 + 1) * QT + r] = v.y;
      A_lds[(k0 + 2) * QT + r] = v.z;
      A_lds[(k0 + 3) * QT + r] = v.w;
    }
  }

  const int qi = t >> 5;
  const int mi = t & 31;

  float tv[4][4];
  int ti[4][4];
#pragma unroll
  for (int j = 0; j < 4; ++j)
#pragma unroll
    for (int s = 0; s < 4; ++s) { tv[j][s] = -FLT_MAX; ti[j][s] = 0x7fffffff; }

  for (int tile = 0; tile < NM / MT; ++tile) {
    const int mbase = tile * MT;
    float acc[4][4];
#pragma unroll
    for (int j = 0; j < 4; ++j)
#pragma unroll
      for (int s = 0; s < 4; ++s) acc[j][s] = 0.0f;

    for (int kb = 0; kb < KD; kb += KC) {
      __syncthreads();
      {
        const int r = t >> 2;
        const int kc = t & 3;
        const float* src = ip + (size_t)(mbase + r) * KD + kb;
#pragma unroll
        for (int i = 0; i < 4; ++i) {
          const int k0 = kc * 4 + i * 16;
          const float4 v = *(const float4*)(src + k0);
          B_lds[(k0 + 0) * MT + r] = v.x;
          B_lds[(k0 + 1) * MT + r] = v.y;
          B_lds[(k0 + 2) * MT + r] = v.z;
          B_lds[(k0 + 3) * MT + r] = v.w;
        }
      }
      __syncthreads();

#pragma unroll 8
      for (int k = 0; k < KC; ++k) {
        const float4 av = *(const float4*)&A_lds[(kb + k) * QT + qi * 4];
        const float4 bv = *(const float4*)&B_lds[k * MT + mi * 4];
        acc[0][0] = fmaf(av.x, bv.x, acc[0][0]);
        acc[0][1] = fmaf(av.x, bv.y, acc[0][1]);
        acc[0][2] = fmaf(av.x, bv.z, acc[0][2]);
        acc[0][3] = fmaf(av.x, bv.w, acc[0][3]);
        acc[1][0] = fmaf(av.y, bv.x, acc[1][0]);
        acc[1][1] = fmaf(av.y, bv.y, acc[1][1]);
        acc[1][2] = fmaf(av.y, bv.z, acc[1][2]);
        acc[1][3] = fmaf(av.y, bv.w, acc[1][3]);
        acc[2][0] = fmaf(av.z, bv.x, acc[2][0]);
        acc[2][1] = fmaf(av.z, bv.y, acc[2][1]);
        acc[2][2] = fmaf(av.z, bv.z, acc[2][2]);
        acc[2][3] = fmaf(av.z, bv.w, acc[2][3]);
        acc[3][0] = fmaf(av.w, bv.x, acc[3][0]);
        acc[3][1] = fmaf(av.w, bv.y, acc[3][1]);
        acc[3][2] = fmaf(av.w, bv.z, acc[3][2]);
        acc[3][3] = fmaf(av.w, bv.w, acc[3][3]);
      }
    }

#pragma unroll
    for (int j = 0; j < 4; ++j) {
#pragma unroll
      for (int s = 0; s < 4; ++s) {
        const float v = acc[j][s];
        const int m = mbase + mi * 4 + s;
        const bool b0 = v > tv[j][0];
        const bool b1 = v > tv[j][1];
        const bool b2 = v > tv[j][2];
        const bool b3 = v > tv[j][3];
        tv[j][3] = b2 ? tv[j][2] : (b3 ? v : tv[j][3]);
        ti[j][3] = b2 ? ti[j][2] : (b3 ? m : ti[j][3]);
        tv[j][2] = b1 ? tv[j][1] : (b2 ? v : tv[j][2]);
        ti[j][2] = b1 ? ti[j][1] : (b2 ? m : ti[j][2]);
        tv[j][1] = b0 ? tv[j][0] : (b1 ? v : tv[j][1]);
        ti[j][1] = b0 ? ti[j][0] : (b1 ? m : ti[j][1]);
        tv[j][0] = b0 ? v : tv[j][0];
        ti[j][0] = b0 ? m : ti[j][0];
      }
    }
  }

  __syncthreads();
  int* idx_lds = (int*)B_lds;
#pragma unroll
  for (int j = 0; j < 4; ++j)
#pragma unroll
    for (int s = 0; s < 4; ++s)
      idx_lds[(qi * 4 + j) * 128 + mi * 4 + s] = ti[j][s];
  __syncthreads();

  double* pv = (double*)A_lds;
  int* piL = (int*)(A_lds + 4096);
  {
    const int r = t >> 3;
    const int slot = t & 7;
    const float* qrow = qp + (size_t)r * KD;
    double bv[4];
    int bi[4];
#pragma unroll
    for (int e = 0; e < 4; ++e) { bv[e] = -DBL_MAX; bi[e] = 0x7fffffff; }

    for (int c = 0; c < 16; ++c) {
      const int m = idx_lds[r * 128 + slot * 16 + c];
      const float* irow = ip + (size_t)m * KD;
      double s0 = 0.0, s1 = 0.0, s2 = 0.0, s3 = 0.0;
#pragma unroll
      for (int k = 0; k < KD; k += 4) {
        const float4 xv = *(const float4*)(qrow + k);
        const float4 yv = *(const float4*)(irow + k);
        s0 = fma((double)xv.x, (double)yv.x, s0);
        s1 = fma((double)xv.y, (double)yv.y, s1);
        s2 = fma((double)xv.z, (double)yv.z, s2);
        s3 = fma((double)xv.w, (double)yv.w, s3);
      }
      const double v = (s0 + s1) + (s2 + s3);
      const bool b0 = BETTER64(v, m, bv[0], bi[0]);
      const bool b1 = BETTER64(v, m, bv[1], bi[1]);
      const bool b2 = BETTER64(v, m, bv[2], bi[2]);
      const bool b3 = BETTER64(v, m, bv[3], bi[3]);
      bv[3] = b2 ? bv[2] : (b3 ? v : bv[3]);
      bi[3] = b2 ? bi[2] : (b3 ? m : bi[3]);
      bv[2] = b1 ? bv[1] : (b2 ? v : bv[2]);
      bi[2] = b1 ? bi[1] : (b2 ? m : bi[2]);
      bv[1] = b0 ? bv[0] : (b1 ? v : bv[1]);
      bi[1] = b0 ? bi[0] : (b1 ? m : bi[1]);
      bv[0] = b0 ? v : bv[0];
      bi[0] = b0 ? m : bi[0];
    }
#pragma unroll
    for (int e = 0; e < 4; ++e) {
      pv[t * 4 + e] = bv[e];
      piL[t * 4 + e] = bi[e];
    }
  }
  __syncthreads();

  if (t < QT) {
    double fv[4];
    int fi[4];
#pragma unroll
    for (int e = 0; e < 4; ++e) { fv[e] = -DBL_MAX; fi[e] = 0x7fffffff; }
    for (int sl = 0; sl < 8; ++sl) {
#pragma unroll
      for (int e = 0; e < 4; ++e) {
        const double v = pv[(t * 8 + sl) * 4 + e];
        const int m = piL[(t * 8 + sl) * 4 + e];
        const bool b0 = BETTER64(v, m, fv[0], fi[0]);
        const bool b1 = BETTER64(v, m, fv[1], fi[1]);
        const bool b2 = BETTER64(v, m, fv[2], fi[2]);
        const bool b3 = BETTER64(v, m, fv[3], fi[3]);
        fv[3] = b2 ? fv[2] : (b3 ? v : fv[3]);
        fi[3] = b2 ? fi[2] : (b3 ? m : fi[3]);
        fv[2] = b1 ? fv[1] : (b2 ? v : fv[2]);
        fi[2] = b1 ? fi[1] : (b2 ? m : fi[2]);
        fv[1] = b0 ? fv[0] : (b1 ? v : fv[1]);
        fi[1] = b0 ? fi[0] : (b1 ? m : fi[1]);
        fv[0] = b0 ? v : fv[0];
        fi[0] = b0 ? m : fi[0];
      }
    }
    int4 o;
    o.x = fi[0]; o.y = fi[1]; o.z = fi[2]; o.w = fi[3];
    *(int4*)(out + ((size_t)b * NQ + qbase + t) * 4) = o;
  }
}

extern "C" void kernel_launch(void* const* d_in, const int* in_sizes, int n_in,
                              void* d_out, int out_size, void* d_ws, size_t ws_size,
                              hipStream_t stream) {
  const float* qry = (const float*)d_in[0];  // (4, 4096, 128) fp32
  const float* img = (const float*)d_in[1];  // (4, 8192, 128) fp32
  int* out = (int*)d_out;                    // (4, 4096, 4) int32

  const size_t qbBytes = (size_t)NBATCH * NQ * KD * sizeof(ushort_t);  // 4 MB
  const size_t ibBytes = (size_t)NBATCH * NM * KD * sizeof(ushort_t);  // 8 MB

  if (ws_size >= qbBytes + ibBytes) {
    ushort_t* qb = (ushort_t*)d_ws;
    int4* ib = (int4*)((char*)d_ws + qbBytes);
    wr_cvt<<<3072, 256, 0, stream>>>(qry, img, qb, ib);
    wr_mfma<<<256, 512, 0, stream>>>(qry, img, qb, ib, out);
  } else {
    wr_main<<<NBATCH * (NQ / QT), NTHREADS, 0, stream>>>(qry, img, out);
  }
}

// Round 3
// 133.562 us; speedup vs baseline: 2.0072x; 2.0072x over previous
//
#include <hip/hip_runtime.h>
#include <float.h>
#include <stdint.h>

// WindowRouting: out[b][q][0..3] = indices of top-4 of (Q[b,q,:] . I[b,m,:]) over m.
// Scale dropped (order-preserving).
//
// R11 = R8's K1 VERBATIM (proven 67.8us, VGPR 100, no scratch) + direct K0.
// R9/R10 post-mortem: group-refine epilogue (unrolled jj over 4 m of a group,
// same qrow) let LICM hoist 32 float4 of qrow across the loop -> VGPR 128 +
// ~1.3KB/thread scratch (176MB WRITE_SIZE) + 4x refine fetch (124MB FETCH).
// Group-max traded non-binding selection VALU for binding regs+HBM. Reverted.
//
// K0 (wr_cvt): fp32 -> bf16, DIRECT (no LDS/sync). One thread = one int4 of the
//   fragment-linear ib layout (gathers 32B of an image row; wave-coalesced into
//   16 full 128B lines), or 8 query elements. Buffers bit-identical to R8's K0.
// K1 (wr_mfma): 256 blocks x 512 thr, launch_bounds(512,1). Block = 64 q x all
//   8192 m. Wave w = m-eighth (64 half-tiles of 16 m). q_per_wave = 64 (4
//   q-strips of 16, bfrag pinned in 64 VGPRs). 3-deep rotating 16-reg image
//   buffers; all 16 MFMAs consume R before refill. Scores -> packed keys
//   (low 11 bits = 2047 - m_local); running top-4 via v_max+3x v_med3 per
//   strip; quad-tree shfl merge (snapshot-first); 32 cand/row -> rank-select
//   top-8 -> fp64 refine vs fp32 originals -> exact top-4 (value desc, idx asc).
// Fallback: fp32 LDS-tiled kernel if ws too small.

#define NBATCH 4
#define NQ 4096
#define NM 8192
#define KD 128

typedef unsigned short ushort_t;
typedef __attribute__((ext_vector_type(8))) short bf16x8;
typedef __attribute__((ext_vector_type(4))) float f32x4;

#define BETTER64(v, i, w, j) (((v) > (w)) || ((v) == (w) && (i) < (j)))

__device__ inline float fmed3(float a, float b, float c) {
#if __has_builtin(__builtin_amdgcn_fmed3f)
  return __builtin_amdgcn_fmed3f(a, b, c);
#else
  return fmaxf(fminf(a, b), fminf(fmaxf(a, b), c));
#endif
}

__device__ inline ushort_t f2bf(float f) {
  unsigned u = __float_as_uint(f);
  u += 0x7fffu + ((u >> 16) & 1u);  // RNE
  return (ushort_t)(u >> 16);
}

__device__ inline unsigned pk2(float a, float b) {
  return (unsigned)f2bf(a) | ((unsigned)f2bf(b) << 16);
}

// ---------------- K0: direct convert + swizzle (no LDS) ----------------
// ib flat int4 index t (within batch): tt = tile*512 + htl*256 + ks*64 + l
//   -> row m = tile*32 + htl*16 + (l&15), k0 = ks*32 + (l>>4)*8, 8 bf16 elems.
__global__ __launch_bounds__(256) void wr_cvt(const float* __restrict__ qry,
                                              const float* __restrict__ img,
                                              ushort_t* __restrict__ qb,
                                              int4* __restrict__ ib) {
  const int t = (int)blockIdx.x * 256 + (int)threadIdx.x;  // 0..786431
  if (t < 524288) {
    // image: one ib int4 per thread
    const int b = t >> 17;
    const int tt = t & 131071;
    const int tile = tt >> 9;
    const int n = tt & 511;
    const int l = n & 63;
    const int m = tile * 32 + (n >> 8) * 16 + (l & 15);
    const int k0 = ((n >> 6) & 3) * 32 + ((l >> 4) & 3) * 8;
    const float* src = img + ((size_t)(b * NM + m)) * KD + k0;
    const float4 v0 = *(const float4*)(src);
    const float4 v1 = *(const float4*)(src + 4);
    int4 o;
    o.x = (int)pk2(v0.x, v0.y);
    o.y = (int)pk2(v0.z, v0.w);
    o.z = (int)pk2(v1.x, v1.y);
    o.w = (int)pk2(v1.z, v1.w);
    ib[t] = o;
  } else {
    // query: 8 elements per thread, linear
    const int u = t - 524288;  // 0..262143
    const float4 v0 = ((const float4*)qry)[2 * u];
    const float4 v1 = ((const float4*)qry)[2 * u + 1];
    int4 o;
    o.x = (int)pk2(v0.x, v0.y);
    o.y = (int)pk2(v0.z, v0.w);
    o.z = (int)pk2(v1.x, v1.y);
    o.w = (int)pk2(v1.z, v1.w);
    ((int4*)qb)[u] = o;
  }
}

// ---------------- K1: MFMA screen + fp64 refine (R8 verbatim) ----------------
__global__ __launch_bounds__(512, 1) void wr_mfma(const float* __restrict__ qry,
                                                  const float* __restrict__ img,
                                                  const ushort_t* __restrict__ qb,
                                                  const int4* __restrict__ ib,
                                                  int* __restrict__ out) {
  const int bid = (int)blockIdx.x;               // 0..255
  const int b = (bid & 7) >> 1;                  // batch pinned to XCD pair
  const int qt = ((bid >> 3) << 1) | (bid & 1);  // 0..63
  const int qbase = qt * 64;

  const int tid = (int)threadIdx.x;
  const int lane = tid & 63;
  const int w = tid >> 6;        // 0..7 -> m-eighth (64 half-tiles of 16 m)
  const int q15 = lane & 15;
  const int quad = lane >> 4;    // 0..3

  const ushort_t* Qb = qb + ((size_t)b * NQ + qbase) * KD;
  const int4* ibc = ib + (size_t)b * 131072;

  // query fragments pinned: 4 strips of 16 q. B[n=q15][k = ks*32 + quad*8 + j]
  bf16x8 bfrag[4][4];  // [strip][ks] -> 64 VGPRs
#pragma unroll
  for (int s = 0; s < 4; ++s)
#pragma unroll
    for (int ks = 0; ks < 4; ++ks)
      bfrag[s][ks] =
          *(const bf16x8*)(Qb + (size_t)(s * 16 + q15) * KD + ks * 32 + quad * 8);

  float tch[4][4];  // one packed-key top-4 chain per strip
#pragma unroll
  for (int s = 0; s < 4; ++s)
#pragma unroll
    for (int e = 0; e < 4; ++e) tch[s][e] = -FLT_MAX;

  bf16x8 B0[4], B1[4], B2[4];  // 3-deep ring, 16 regs each

  auto loadH = [&](bf16x8* R, int h) {
    const int4* p = ibc + (((w * 64 + h) << 8) + lane);
#pragma unroll
    for (int ks = 0; ks < 4; ++ks) R[ks] = *(const bf16x8*)(p + ks * 64);
  };

  int hl = 3;
  int vb = 2047 - 4 * quad;  // key base; m_local = 16*h + 4*quad + r  (< 1024)

  auto step = [&](bf16x8* R) {
    f32x4 a[4];
#pragma unroll
    for (int s = 0; s < 4; ++s) a[s] = {0.f, 0.f, 0.f, 0.f};
    // all 16 MFMAs consume R before the refill below (ring-reuse hazard)
#pragma unroll
    for (int ks = 0; ks < 4; ++ks)
#pragma unroll
      for (int s = 0; s < 4; ++s)
        a[s] = __builtin_amdgcn_mfma_f32_16x16x32_bf16(R[ks], bfrag[s][ks], a[s],
                                                       0, 0, 0);
    if (hl < 64) loadH(R, hl);  // refill for use 3 steps later
    ++hl;
#pragma unroll
    for (int s = 0; s < 4; ++s) {
#pragma unroll
      for (int r = 0; r < 4; ++r) {
        const unsigned kr = (unsigned)(vb - r);
        const float k =
            __uint_as_float((__float_as_uint(a[s][r]) & 0xFFFFF800u) | kr);
        tch[s][3] = fmed3(k, tch[s][2], tch[s][3]);
        tch[s][2] = fmed3(k, tch[s][1], tch[s][2]);
        tch[s][1] = fmed3(k, tch[s][0], tch[s][1]);
        tch[s][0] = fmaxf(tch[s][0], k);
      }
    }
    vb -= 16;
  };

  loadH(B0, 0);
  loadH(B1, 1);
  loadH(B2, 2);
  for (int g = 0; g < 21; ++g) { step(B0); step(B1); step(B2); }
  step(B0);  // half-tile 63

  // ---- quad-tree merge per strip (snapshot donor regs BEFORE mutating) ----
#pragma unroll
  for (int s = 0; s < 4; ++s) {
    float k4[4];
#pragma unroll
    for (int e = 0; e < 4; ++e) k4[e] = __shfl_down(tch[s][e], 32, 64);
#pragma unroll
    for (int e = 0; e < 4; ++e) {
      const float k = k4[e];
      tch[s][3] = fmed3(k, tch[s][2], tch[s][3]);
      tch[s][2] = fmed3(k, tch[s][1], tch[s][2]);
      tch[s][1] = fmed3(k, tch[s][0], tch[s][1]);
      tch[s][0] = fmaxf(tch[s][0], k);
    }
#pragma unroll
    for (int e = 0; e < 4; ++e) k4[e] = __shfl_down(tch[s][e], 16, 64);
#pragma unroll
    for (int e = 0; e < 4; ++e) {
      const float k = k4[e];
      tch[s][3] = fmed3(k, tch[s][2], tch[s][3]);
      tch[s][2] = fmed3(k, tch[s][1], tch[s][2]);
      tch[s][1] = fmed3(k, tch[s][0], tch[s][1]);
      tch[s][0] = fmaxf(tch[s][0], k);
    }
  }

  // ---- 32 candidates per q-row (8 eighths x 4), 64 rows ----
  __shared__ float ck[64][33];
  __shared__ int top8[64][8];
  __shared__ double pd[64][8];
  __shared__ int pi[64][8];

  if (lane < 16) {
#pragma unroll
    for (int s = 0; s < 4; ++s)
#pragma unroll
      for (int e = 0; e < 4; ++e) ck[s * 16 + q15][w * 4 + e] = tch[s][e];
  }
  __syncthreads();

  // ---- rank-select top-8 of 32 packed keys per row (ranks unique) ----
  for (int p = tid; p < 2048; p += 512) {
    const int q = p >> 5;
    const int j = p & 31;
    const float k = ck[q][j];
    int rank = 0;
#pragma unroll 8
    for (int i = 0; i < 32; ++i) {
      const float o = ck[q][i];
      rank += (o > k) || (o == k && i < j);
    }
    if (rank < 8) {
      const unsigned bits = __float_as_uint(k);
      top8[q][rank] = (j >> 2) * 1024 + 2047 - (int)(bits & 0x7FFu);
    }
  }
  __syncthreads();

  // ---- fp64 refine: one candidate per thread (64 rows x 8) ----
  {
    const int q = tid >> 3;
    const int slot = tid & 7;
    const int m = top8[q][slot];
    const float* qrow = qry + ((size_t)b * NQ + qbase + q) * KD;
    const float* irow = img + ((size_t)b * NM + m) * KD;
    double s0 = 0.0, s1 = 0.0, s2 = 0.0, s3 = 0.0;
#pragma unroll
    for (int k = 0; k < KD; k += 4) {
      const float4 xv = *(const float4*)(qrow + k);
      const float4 yv = *(const float4*)(irow + k);
      s0 = fma((double)xv.x, (double)yv.x, s0);
      s1 = fma((double)xv.y, (double)yv.y, s1);
      s2 = fma((double)xv.z, (double)yv.z, s2);
      s3 = fma((double)xv.w, (double)yv.w, s3);
    }
    pd[q][slot] = (s0 + s1) + (s2 + s3);
    pi[q][slot] = m;
  }
  __syncthreads();

  // ---- exact top-4 of 8 refined, (value desc, index asc) ----
  if (tid < 64) {
    const int q = tid;
    double fv[4];
    int fi[4];
#pragma unroll
    for (int e = 0; e < 4; ++e) { fv[e] = -DBL_MAX; fi[e] = 0x7fffffff; }
    for (int sl = 0; sl < 8; ++sl) {
      const double v = pd[q][sl];
      const int m = pi[q][sl];
      const bool b0 = BETTER64(v, m, fv[0], fi[0]);
      const bool b1 = BETTER64(v, m, fv[1], fi[1]);
      const bool b2 = BETTER64(v, m, fv[2], fi[2]);
      const bool b3 = BETTER64(v, m, fv[3], fi[3]);
      fv[3] = b2 ? fv[2] : (b3 ? v : fv[3]);
      fi[3] = b2 ? fi[2] : (b3 ? m : fi[3]);
      fv[2] = b1 ? fv[1] : (b2 ? v : fv[2]);
      fi[2] = b1 ? fi[1] : (b2 ? m : fi[2]);
      fv[1] = b0 ? fv[0] : (b1 ? v : fv[1]);
      fi[1] = b0 ? fi[0] : (b1 ? m : fi[1]);
      fv[0] = b0 ? v : fv[0];
      fi[0] = b0 ? m : fi[0];
    }
    int4 o;
    o.x = fi[0]; o.y = fi[1]; o.z = fi[2]; o.w = fi[3];
    *(int4*)(out + ((size_t)b * NQ + qbase + q) * 4) = o;
  }
}

// ---------------- Fallback: fp32 LDS-tiled kernel (ws too small) ----------------
#define QT 64
#define MT 128
#define KC 64
#define NTHREADS 512

__global__ __launch_bounds__(NTHREADS) void wr_main(const float* __restrict__ qry,
                                                    const float* __restrict__ img,
                                                    int* __restrict__ out) {
  __shared__ __align__(16) float A_lds[KD * QT];
  __shared__ __align__(16) float B_lds[KC * MT];

  const int t = (int)threadIdx.x;
  const int b = (int)blockIdx.x >> 6;
  const int qbase = ((int)blockIdx.x & 63) * QT;

  const float* qp = qry + ((size_t)b * NQ + qbase) * KD;
  const float* ip = img + (size_t)b * NM * KD;

  {
    const int r = t >> 3;
    const int kc = t & 7;
    const float* src = qp + (size_t)r * KD;
#pragma unroll
    for (int i = 0; i < 4; ++i) {
      const int k0 = kc * 4 + i * 32;
      const float4 v = *(const float4*)(src + k0);
      A_lds[(k0 + 0) * QT + r] = v.x;
      A_lds[(k0 + 1) * QT + r] = v.y;
      A_lds[(k0 + 2) * QT + r] = v.z;
      A_lds[(k0 + 3) * QT + r] = v.w;
    }
  }

  const int qi = t >> 5;
  const int mi = t & 31;

  float tv[4][4];
  int ti[4][4];
#pragma unroll
  for (int j = 0; j < 4; ++j)
#pragma unroll
    for (int s = 0; s < 4; ++s) { tv[j][s] = -FLT_MAX; ti[j][s] = 0x7fffffff; }

  for (int tile = 0; tile < NM / MT; ++tile) {
    const int mbase = tile * MT;
    float acc[4][4];
#pragma unroll
    for (int j = 0; j < 4; ++j)
#pragma unroll
      for (int s = 0; s < 4; ++s) acc[j][s] = 0.0f;

    for (int kb = 0; kb < KD; kb += KC) {
      __syncthreads();
      {
        const int r = t >> 2;
        const int kc = t & 3;
        const float* src = ip + (size_t)(mbase + r) * KD + kb;
#pragma unroll
        for (int i = 0; i < 4; ++i) {
          const int k0 = kc * 4 + i * 16;
          const float4 v = *(const float4*)(src + k0);
          B_lds[(k0 + 0) * MT + r] = v.x;
          B_lds[(k0 + 1) * MT + r] = v.y;
          B_lds[(k0 + 2) * MT + r] = v.z;
          B_lds[(k0 + 3) * MT + r] = v.w;
        }
      }
      __syncthreads();

#pragma unroll 8
      for (int k = 0; k < KC; ++k) {
        const float4 av = *(const float4*)&A_lds[(kb + k) * QT + qi * 4];
        const float4 bv = *(const float4*)&B_lds[k * MT + mi * 4];
        acc[0][0] = fmaf(av.x, bv.x, acc[0][0]);
        acc[0][1] = fmaf(av.x, bv.y, acc[0][1]);
        acc[0][2] = fmaf(av.x, bv.z, acc[0][2]);
        acc[0][3] = fmaf(av.x, bv.w, acc[0][3]);
        acc[1][0] = fmaf(av.y, bv.x, acc[1][0]);
        acc[1][1] = fmaf(av.y, bv.y, acc[1][1]);
        acc[1][2] = fmaf(av.y, bv.z, acc[1][2]);
        acc[1][3] = fmaf(av.y, bv.w, acc[1][3]);
        acc[2][0] = fmaf(av.z, bv.x, acc[2][0]);
        acc[2][1] = fmaf(av.z, bv.y, acc[2][1]);
        acc[2][2] = fmaf(av.z, bv.z, acc[2][2]);
        acc[2][3] = fmaf(av.z, bv.w, acc[2][3]);
        acc[3][0] = fmaf(av.w, bv.x, acc[3][0]);
        acc[3][1] = fmaf(av.w, bv.y, acc[3][1]);
        acc[3][2] = fmaf(av.w, bv.z, acc[3][2]);
        acc[3][3] = fmaf(av.w, bv.w, acc[3][3]);
      }
    }

#pragma unroll
    for (int j = 0; j < 4; ++j) {
#pragma unroll
      for (int s = 0; s < 4; ++s) {
        const float v = acc[j][s];
        const int m = mbase + mi * 4 + s;
        const bool b0 = v > tv[j][0];
        const bool b1 = v > tv[j][1];
        const bool b2 = v > tv[j][2];
        const bool b3 = v > tv[j][3];
        tv[j][3] = b2 ? tv[j][2] : (b3 ? v : tv[j][3]);
        ti[j][3] = b2 ? ti[j][2] : (b3 ? m : ti[j][3]);
        tv[j][2] = b1 ? tv[j][1] : (b2 ? v : tv[j][2]);
        ti[j][2] = b1 ? ti[j][1] : (b2 ? m : ti[j][2]);
        tv[j][1] = b0 ? tv[j][0] : (b1 ? v : tv[j][1]);
        ti[j][1] = b0 ? ti[j][0] : (b1 ? m : ti[j][1]);
        tv[j][0] = b0 ? v : tv[j][0];
        ti[j][0] = b0 ? m : ti[j][0];
      }
    }
  }

  __syncthreads();
  int* idx_lds = (int*)B_lds;
#pragma unroll
  for (int j = 0; j < 4; ++j)
#pragma unroll
    for (int s = 0; s < 4; ++s)
      idx_lds[(qi * 4 + j) * 128 + mi * 4 + s] = ti[j][s];
  __syncthreads();

  double* pv = (double*)A_lds;
  int* piL = (int*)(A_lds + 4096);
  {
    const int r = t >> 3;
    const int slot = t & 7;
    const float* qrow = qp + (size_t)r * KD;
    double bv[4];
    int bi[4];
#pragma unroll
    for (int e = 0; e < 4; ++e) { bv[e] = -DBL_MAX; bi[e] = 0x7fffffff; }

    for (int c = 0; c < 16; ++c) {
      const int m = idx_lds[r * 128 + slot * 16 + c];
      const float* irow = ip + (size_t)m * KD;
      double s0 = 0.0, s1 = 0.0, s2 = 0.0, s3 = 0.0;
#pragma unroll
      for (int k = 0; k < KD; k += 4) {
        const float4 xv = *(const float4*)(qrow + k);
        const float4 yv = *(const float4*)(irow + k);
        s0 = fma((double)xv.x, (double)yv.x, s0);
        s1 = fma((double)xv.y, (double)yv.y, s1);
        s2 = fma((double)xv.z, (double)yv.z, s2);
        s3 = fma((double)xv.w, (double)yv.w, s3);
      }
      const double v = (s0 + s1) + (s2 + s3);
      const bool b0 = BETTER64(v, m, bv[0], bi[0]);
      const bool b1 = BETTER64(v, m, bv[1], bi[1]);
      const bool b2 = BETTER64(v, m, bv[2], bi[2]);
      const bool b3 = BETTER64(v, m, bv[3], bi[3]);
      bv[3] = b2 ? bv[2] : (b3 ? v : bv[3]);
      bi[3] = b2 ? bi[2] : (b3 ? m : bi[3]);
      bv[2] = b1 ? bv[1] : (b2 ? v : bv[2]);
      bi[2] = b1 ? bi[1] : (b2 ? m : bi[2]);
      bv[1] = b0 ? bv[0] : (b1 ? v : bv[1]);
      bi[1] = b0 ? bi[0] : (b1 ? m : bi[1]);
      bv[0] = b0 ? v : bv[0];
      bi[0] = b0 ? m : bi[0];
    }
#pragma unroll
    for (int e = 0; e < 4; ++e) {
      pv[t * 4 + e] = bv[e];
      piL[t * 4 + e] = bi[e];
    }
  }
  __syncthreads();

  if (t < QT) {
    double fv[4];
    int fi[4];
#pragma unroll
    for (int e = 0; e < 4; ++e) { fv[e] = -DBL_MAX; fi[e] = 0x7fffffff; }
    for (int sl = 0; sl < 8; ++sl) {
#pragma unroll
      for (int e = 0; e < 4; ++e) {
        const double v = pv[(t * 8 + sl) * 4 + e];
        const int m = piL[(t * 8 + sl) * 4 + e];
        const bool b0 = BETTER64(v, m, fv[0], fi[0]);
        const bool b1 = BETTER64(v, m, fv[1], fi[1]);
        const bool b2 = BETTER64(v, m, fv[2], fi[2]);
        const bool b3 = BETTER64(v, m, fv[3], fi[3]);
        fv[3] = b2 ? fv[2] : (b3 ? v : fv[3]);
        fi[3] = b2 ? fi[2] : (b3 ? m : fi[3]);
        fv[2] = b1 ? fv[1] : (b2 ? v : fv[2]);
        fi[2] = b1 ? fi[1] : (b2 ? m : fi[2]);
        fv[1] = b0 ? fv[0] : (b1 ? v : fv[1]);
        fi[1] = b0 ? fi[0] : (b1 ? m : fi[1]);
        fv[0] = b0 ? v : fv[0];
        fi[0] = b0 ? m : fi[0];
      }
    }
    int4 o;
    o.x = fi[0]; o.y = fi[1]; o.z = fi[2]; o.w = fi[3];
    *(int4*)(out + ((size_t)b * NQ + qbase + t) * 4) = o;
  }
}

extern "C" void kernel_launch(void* const* d_in, const int* in_sizes, int n_in,
                              void* d_out, int out_size, void* d_ws, size_t ws_size,
                              hipStream_t stream) {
  const float* qry = (const float*)d_in[0];  // (4, 4096, 128) fp32
  const float* img = (const float*)d_in[1];  // (4, 8192, 128) fp32
  int* out = (int*)d_out;                    // (4, 4096, 4) int32

  const size_t qbBytes = (size_t)NBATCH * NQ * KD * sizeof(ushort_t);  // 4 MB
  const size_t ibBytes = (size_t)NBATCH * NM * KD * sizeof(ushort_t);  // 8 MB

  if (ws_size >= qbBytes + ibBytes) {
    ushort_t* qb = (ushort_t*)d_ws;
    int4* ib = (int4*)((char*)d_ws + qbBytes);
    wr_cvt<<<3072, 256, 0, stream>>>(qry, img, qb, ib);
    wr_mfma<<<256, 512, 0, stream>>>(qry, img, qb, ib, out);
  } else {
    wr_main<<<NBATCH * (NQ / QT), NTHREADS, 0, stream>>>(qry, img, out);
  }
}